// Round 13
// baseline (242.108 us; speedup 1.0000x reference)
//
#include <hip/hip_runtime.h>

#define B_    4
#define C_    256
#define H_    64
#define W_    64
#define HW_   4096
#define NG_   32
#define CPG_  8
#define KK_   9
#define NOFF_ 18

typedef __attribute__((ext_vector_type(8))) short short8;
typedef __attribute__((ext_vector_type(4))) short short4v;
typedef __attribute__((ext_vector_type(4))) float floatx4;
typedef __attribute__((ext_vector_type(16))) float floatx16;

static __device__ __forceinline__ short f2bf(float f) {
    union { float f; unsigned u; } v; v.f = f;
    unsigned r = v.u + 0x7fff + ((v.u >> 16) & 1);   // RNE
    return (short)(r >> 16);
}
static __device__ __forceinline__ float bf2f(short s) {
    union { unsigned u; float f; } v;
    v.u = ((unsigned)(unsigned short)s) << 16;
    return v.f;
}
// packed f32x2 -> bf16x2 (RNE), single VALU op
static __device__ __forceinline__ unsigned pkbf(float lo, float hi) {
    unsigned r;
    asm("v_cvt_pk_bf16_f32 %0, %1, %2" : "=v"(r) : "v"(lo), "v"(hi));
    return r;
}

// ---------------------------------------------------------------------------
// K3: pack weights + gn1 stats (one launch, grid 4800).
// Blocks 0..4607: w1/w2 (coalesced fp32 reads, scattered 2B writes).
// Blocks 4608..4671: pw1/pw2.
// Blocks 4672..4799: gn1 stats -- one block per (b,group): reduce the 128KB
// fp32 slab of x to {mean, rsqrt(var+eps)} written directly (no partials).
// ---------------------------------------------------------------------------
__global__ __launch_bounds__(256) void wpack_gn1_kernel(
    const float* __restrict__ w1, const float* __restrict__ w2,
    const float* __restrict__ pw1, const float* __restrict__ pw2,
    short* __restrict__ wp1, short* __restrict__ wp2,
    short* __restrict__ ppk1, short* __restrict__ ppk2,
    const float* __restrict__ xin, float* __restrict__ gstats)
{
    __shared__ float red[8];
    int blk = blockIdx.x;
    if (blk < 4608) {
        const float* w = (blk < 2304) ? w1 : w2;
        short* wp = (blk < 2304) ? wp1 : wp2;
        int src = (blk % 2304) * 256 + threadIdx.x;  // 0..589823, coalesced
        float v = w[src];
        int o = src / (C_ * KK_);                    // src = (o*C + c)*9 + g
        int r = src - o * (C_ * KK_);
        int c = r / KK_;
        int g = r - c * KK_;
        int ot   = o >> 5;
        int lane = (o & 31) | (((c >> 3) & 1) << 5);
        int j    = c & 7;
        int slab = g * 16 + (c >> 4);
        wp[(slab << 12) | (ot << 9) | (lane << 3) | j] = f2bf(v);
    } else if (blk < 4672) {
        int q = blk - 4608;                          // 0..63
        const float* pw = (q < 32) ? pw1 : pw2;
        short* ppk = (q < 32) ? ppk1 : ppk2;
        int idx = (q & 31) * 256 + threadIdx.x;      // 0..8191
        int j = idx & 7, lane = (idx >> 3) & 63;
        int ot = (idx >> 9) & 1, sl = idx >> 10;     // 0..7
        int o = ot * 16 + (lane & 15);
        int k = sl * 32 + (lane >> 4) * 8 + j;
        ppk[idx] = (o < NOFF_) ? f2bf(pw[o * C_ + k]) : (short)0;
    } else {
        int q = blk - 4672;                          // 0..127
        int b = q >> 5, g = q & 31;
        const int N = CPG_ * HW_;                    // 32768
        size_t base = ((size_t)(b * C_ + g * CPG_)) * HW_;
        const float4* in4 = (const float4*)(xin + base);
        int t = threadIdx.x;
        float s = 0.f, ss = 0.f;
        for (int i = t; i < N / 4; i += 256) {
            float4 v = in4[i];
            s  += v.x + v.y + v.z + v.w;
            ss += v.x * v.x + v.y * v.y + v.z * v.z + v.w * v.w;
        }
        #pragma unroll
        for (int off = 32; off > 0; off >>= 1) {
            s  += __shfl_down(s, off, 64);
            ss += __shfl_down(ss, off, 64);
        }
        int wid = t >> 6;
        if ((t & 63) == 0) { red[wid] = s; red[4 + wid] = ss; }
        __syncthreads();
        if (t == 0) {
            float S = red[0] + red[1] + red[2] + red[3];
            float SS = red[4] + red[5] + red[6] + red[7];
            float m = S / (float)N;
            float var = SS / (float)N - m * m;
            gstats[b * 32 + g] = m;
            gstats[128 + b * 32 + g] = rsqrtf(var + 1e-5f);
        }
    }
}

// ---------------------------------------------------------------------------
// K2a (layer 1): fused {gn1-apply + depthwise 7x7 -> fdwt} AND {gn1-apply +
// transpose -> ht [B][HW][C]}, reading x in fp32 directly (stats from the
// wpack launch). The standalone gn1 kernel and its hbf round-trip are gone.
// Blocks 0..255: dw7t (b, o8, rh); group == o8. Blocks 256..511: trA.
// ---------------------------------------------------------------------------
__global__ __launch_bounds__(256) void dw7t_tr_f32_kernel(
    const float* __restrict__ in,   // x [B][C][HW] fp32
    const float* __restrict__ dwk,  // [C][49]
    short* __restrict__ fdwt,       // [B][64][32][64][8]
    short* __restrict__ ht,         // [B][HW][C]
    const float* __restrict__ gstats,  // [2][128]: m | rs
    const float* __restrict__ gamma, const float* __restrict__ beta)
{
    __shared__ __align__(16) char smem[78144];
    int t = threadIdx.x;
    int blk = blockIdx.x;
    if (blk < 256) {
        short (*tile)[38][72] = (short(*)[38][72])smem;          // 43776 B
        float (*wk8)[49]      = (float(*)[49])(smem + 43776);    // 1568 B
        short (*outs)[2048]   = (short(*)[2048])(smem + 45344);  // 32768 B
        int b = blk >> 6, o8 = (blk >> 1) & 31, rh = blk & 1;
        int c0 = o8 * 8;
        int sidx = b * 32 + o8;
        float m_g = gstats[sidx], rs_g = gstats[128 + sidx];
        unsigned* tz = (unsigned*)smem;
        for (int i = t; i < 10944; i += 256) tz[i] = 0u;         // zero tile
        for (int i = t; i < 392; i += 256)
            wk8[i / 49][i % 49] = dwk[(c0 + i / 49) * 49 + (i % 49)];
        __syncthreads();
        // load 8 fp32 planes with gn+relu, rows rh*32-3 .. +34, cols +4 pad
        for (int ch = 0; ch < 8; ++ch) {
            const float* src = in + ((size_t)(b * C_ + c0 + ch)) * HW_;
            float ga = gamma[c0 + ch] * rs_g;
            float be = beta[c0 + ch] - m_g * ga;
            for (int i = t; i < 608; i += 256) {
                int rr = i >> 4, xq = i & 15;
                int ry = rh * 32 + rr - 3;
                if (ry >= 0 && ry < 64) {
                    float4 v = *(const float4*)(src + ry * 64 + xq * 4);
                    short4v o;
                    o.x = f2bf(fmaxf(fmaf(v.x, ga, be), 0.f));
                    o.y = f2bf(fmaxf(fmaf(v.y, ga, be), 0.f));
                    o.z = f2bf(fmaxf(fmaf(v.z, ga, be), 0.f));
                    o.w = f2bf(fmaxf(fmaf(v.w, ga, be), 0.f));
                    *(short4v*)&tile[ch][rr][4 + xq * 4] = o;
                }
            }
        }
        __syncthreads();
        // compute: 4096 quads (ch,y,x0)
        for (int it = 0; it < 16; ++it) {
            int q = it * 256 + t;
            int ch = q >> 9, y = (q >> 4) & 31, x0 = (q & 15) << 2;
            float a0 = 0.f, a1 = 0.f, a2 = 0.f, a3 = 0.f;
            const float* wr0 = wk8[ch];
            #pragma unroll
            for (int dy = 0; dy < 7; ++dy) {
                const short* trw = &tile[ch][y + dy][x0];
                short4v s0 = *(const short4v*)trw;
                short4v s1 = *(const short4v*)(trw + 4);
                short4v s2 = *(const short4v*)(trw + 8);
                float r[12] = {bf2f(s0.x), bf2f(s0.y), bf2f(s0.z), bf2f(s0.w),
                               bf2f(s1.x), bf2f(s1.y), bf2f(s1.z), bf2f(s1.w),
                               bf2f(s2.x), bf2f(s2.y), bf2f(s2.z), bf2f(s2.w)};
                const float* wr = wr0 + dy * 7;
                #pragma unroll
                for (int dx = 0; dx < 7; ++dx) {
                    float wv = wr[dx];
                    a0 = fmaf(r[dx + 1], wv, a0);
                    a1 = fmaf(r[dx + 2], wv, a1);
                    a2 = fmaf(r[dx + 3], wv, a2);
                    a3 = fmaf(r[dx + 4], wv, a3);
                }
            }
            short4v o;
            o.x = f2bf(a0); o.y = f2bf(a1); o.z = f2bf(a2); o.w = f2bf(a3);
            *(short4v*)&outs[ch][y * 64 + x0] = o;
        }
        __syncthreads();
        for (int it = 0; it < 8; ++it) {
            int p = it * 256 + t;
            short8 v;
            #pragma unroll
            for (int ch = 0; ch < 8; ++ch) v[ch] = outs[ch][p];
            *(short8*)(fdwt + (((size_t)(b * 64 + rh * 32 + (p >> 6)) * 32 + o8) * 64
                               + (p & 63)) * 8) = v;
        }
    } else {
        unsigned* ltile = (unsigned*)smem;     // 33792 B
        float* gmrs = (float*)(smem + 65536);  // 64 floats (m | rs)
        int q0 = blk - 256;
        int q = ((q0 & 7) << 5) | (q0 >> 3);   // XCD swizzle (matches deform)
        int b = q >> 6;
        int px0 = (q & 63) * 64;
        const float* sb = in + (size_t)b * C_ * HW_;
        if (t < 32) {
            gmrs[t] = gstats[b * 32 + t];
            gmrs[32 + t] = gstats[128 + b * 32 + t];
        }
        __syncthreads();
        int pq4 = t & 15, cphi = t >> 4;
        #pragma unroll
        for (int i = 0; i < 8; ++i) {
            int cp = i * 16 + cphi;            // channel pair 0..127
            const float* r0 = sb + (size_t)(2 * cp) * HW_ + px0 + pq4 * 4;
            float4 flo = *(const float4*)r0;
            float4 fhi = *(const float4*)(r0 + HW_);
            int g0 = cp >> 2;
            float mm = gmrs[g0], rr2 = gmrs[32 + g0];
            float ga0 = gamma[2 * cp] * rr2;     float be0 = beta[2 * cp] - mm * ga0;
            float ga1 = gamma[2 * cp + 1] * rr2; float be1 = beta[2 * cp + 1] - mm * ga1;
            float lo[4] = {flo.x, flo.y, flo.z, flo.w};
            float hi[4] = {fhi.x, fhi.y, fhi.z, fhi.w};
            #pragma unroll
            for (int j = 0; j < 4; ++j) {
                int pl = pq4 * 4 + j;
                float v0 = fmaxf(fmaf(lo[j], ga0, be0), 0.f);
                float v1 = fmaxf(fmaf(hi[j], ga1, be1), 0.f);
                ltile[pl * 132 + (cp ^ ((pl & 7) << 2))] = pkbf(v0, v1);
            }
        }
        __syncthreads();
        int co = t & 31, ph2 = t >> 5;
        #pragma unroll
        for (int r = 0; r < 8; ++r) {
            int pl = r * 8 + ph2;
            uint4 v = *(const uint4*)&ltile[pl * 132 + ((co * 4) ^ ((pl & 7) << 2))];
            *(uint4*)(ht + ((size_t)b * HW_ + px0 + pl) * C_ + co * 8) = v;
        }
    }
}

// ---------------------------------------------------------------------------
// K2b (layer 2): r12-proven dw7t_tr with fused gn2-apply from deform-1's
// per-row partials. Blocks 0..255: dw7t. Blocks 256..511: trA.
// ---------------------------------------------------------------------------
__global__ __launch_bounds__(256) void dw7t_tr_kernel(
    const short* __restrict__ in,   // y1b [B][C][HW]
    const float* __restrict__ dwk,  // [C][49]
    short* __restrict__ fdwt,       // [B][64][32][64][8]
    short* __restrict__ ht,         // [B][HW][C]
    const float* __restrict__ pstats,  // [B][64][32][2]
    const float* __restrict__ gamma, const float* __restrict__ beta)
{
    __shared__ __align__(16) char smem[78144];
    const float Ninv = 1.f / (float)(CPG_ * HW_);
    int t = threadIdx.x;
    int blk = blockIdx.x;
    if (blk < 256) {
        short (*tile)[38][72] = (short(*)[38][72])smem;          // 43776 B
        float (*wk8)[49]      = (float(*)[49])(smem + 43776);    // 1568 B
        short (*outs)[2048]   = (short(*)[2048])(smem + 45344);  // 32768 B
        float* gsh            = (float*)(smem + 78112);          // 2 floats
        int b = blk >> 6, o8 = (blk >> 1) & 31, rh = blk & 1;
        int c0 = o8 * 8;
        if (t < 64) {
            const float* pp = pstats + (((size_t)(b * 64 + t)) * 32 + o8) * 2;
            float s = pp[0], q = pp[1];
            #pragma unroll
            for (int off = 32; off > 0; off >>= 1) {
                s += __shfl_down(s, off, 64);
                q += __shfl_down(q, off, 64);
            }
            if (t == 0) {
                float m = s * Ninv;
                float var = q * Ninv - m * m;
                gsh[0] = m;
                gsh[1] = rsqrtf(var + 1e-5f);
            }
        }
        unsigned* tz = (unsigned*)smem;
        for (int i = t; i < 10944; i += 256) tz[i] = 0u;         // zero tile
        for (int i = t; i < 392; i += 256)
            wk8[i / 49][i % 49] = dwk[(c0 + i / 49) * 49 + (i % 49)];
        __syncthreads();
        float m_g = gsh[0], rs_g = gsh[1];
        for (int ch = 0; ch < 8; ++ch) {
            const short* src = in + ((size_t)(b * C_ + c0 + ch)) * HW_;
            float ga = gamma[c0 + ch] * rs_g;
            float be = beta[c0 + ch] - m_g * ga;
            for (int i = t; i < 608; i += 256) {
                int rr = i >> 4, xq = i & 15;
                int ry = rh * 32 + rr - 3;
                if (ry >= 0 && ry < 64) {
                    short4v v = *(const short4v*)(src + ry * 64 + xq * 4);
                    v.x = f2bf(fmaxf(fmaf(bf2f(v.x), ga, be), 0.f));
                    v.y = f2bf(fmaxf(fmaf(bf2f(v.y), ga, be), 0.f));
                    v.z = f2bf(fmaxf(fmaf(bf2f(v.z), ga, be), 0.f));
                    v.w = f2bf(fmaxf(fmaf(bf2f(v.w), ga, be), 0.f));
                    *(short4v*)&tile[ch][rr][4 + xq * 4] = v;
                }
            }
        }
        __syncthreads();
        for (int it = 0; it < 16; ++it) {
            int q = it * 256 + t;
            int ch = q >> 9, y = (q >> 4) & 31, x0 = (q & 15) << 2;
            float a0 = 0.f, a1 = 0.f, a2 = 0.f, a3 = 0.f;
            const float* wr0 = wk8[ch];
            #pragma unroll
            for (int dy = 0; dy < 7; ++dy) {
                const short* trw = &tile[ch][y + dy][x0];
                short4v s0 = *(const short4v*)trw;
                short4v s1 = *(const short4v*)(trw + 4);
                short4v s2 = *(const short4v*)(trw + 8);
                float r[12] = {bf2f(s0.x), bf2f(s0.y), bf2f(s0.z), bf2f(s0.w),
                               bf2f(s1.x), bf2f(s1.y), bf2f(s1.z), bf2f(s1.w),
                               bf2f(s2.x), bf2f(s2.y), bf2f(s2.z), bf2f(s2.w)};
                const float* wr = wr0 + dy * 7;
                #pragma unroll
                for (int dx = 0; dx < 7; ++dx) {
                    float wv = wr[dx];
                    a0 = fmaf(r[dx + 1], wv, a0);
                    a1 = fmaf(r[dx + 2], wv, a1);
                    a2 = fmaf(r[dx + 3], wv, a2);
                    a3 = fmaf(r[dx + 4], wv, a3);
                }
            }
            short4v o;
            o.x = f2bf(a0); o.y = f2bf(a1); o.z = f2bf(a2); o.w = f2bf(a3);
            *(short4v*)&outs[ch][y * 64 + x0] = o;
        }
        __syncthreads();
        for (int it = 0; it < 8; ++it) {
            int p = it * 256 + t;
            short8 v;
            #pragma unroll
            for (int ch = 0; ch < 8; ++ch) v[ch] = outs[ch][p];
            *(short8*)(fdwt + (((size_t)(b * 64 + rh * 32 + (p >> 6)) * 32 + o8) * 64
                               + (p & 63)) * 8) = v;
        }
    } else {
        unsigned* ltile = (unsigned*)smem;     // 33792 B
        float* gmrs = (float*)(smem + 65536);  // 64 floats (m | rs)
        int q0 = blk - 256;
        int q = ((q0 & 7) << 5) | (q0 >> 3);   // XCD swizzle (matches deform)
        int b = q >> 6;
        int px0 = (q & 63) * 64;
        const short* sb = in + (size_t)b * C_ * HW_;
        {
            int gq = t >> 3, rq = t & 7;
            float s = 0.f, qs = 0.f;
            for (int rr = rq; rr < 64; rr += 8) {
                const float* pp = pstats + (((size_t)(b * 64 + rr)) * 32 + gq) * 2;
                s += pp[0]; qs += pp[1];
            }
            s  += __shfl_down(s, 4, 64);  qs += __shfl_down(qs, 4, 64);
            s  += __shfl_down(s, 2, 64);  qs += __shfl_down(qs, 2, 64);
            s  += __shfl_down(s, 1, 64);  qs += __shfl_down(qs, 1, 64);
            if (rq == 0) {
                float m = s * Ninv;
                float var = qs * Ninv - m * m;
                gmrs[gq] = m;
                gmrs[32 + gq] = rsqrtf(var + 1e-5f);
            }
        }
        __syncthreads();
        int pq4 = t & 15, cphi = t >> 4;
        #pragma unroll
        for (int i = 0; i < 8; ++i) {
            int cp = i * 16 + cphi;            // channel pair 0..127
            const short* r0 = sb + (size_t)(2 * cp) * HW_ + px0 + pq4 * 4;
            short4v lo = *(const short4v*)r0;
            short4v hi = *(const short4v*)(r0 + HW_);
            int g0 = cp >> 2;
            float mm = gmrs[g0], rr2 = gmrs[32 + g0];
            float ga0 = gamma[2 * cp] * rr2;     float be0 = beta[2 * cp] - mm * ga0;
            float ga1 = gamma[2 * cp + 1] * rr2; float be1 = beta[2 * cp + 1] - mm * ga1;
            #pragma unroll
            for (int j = 0; j < 4; ++j) {
                int pl = pq4 * 4 + j;
                float v0 = fmaxf(fmaf(bf2f(lo[j]), ga0, be0), 0.f);
                float v1 = fmaxf(fmaf(bf2f(hi[j]), ga1, be1), 0.f);
                ltile[pl * 132 + (cp ^ ((pl & 7) << 2))] = pkbf(v0, v1);
            }
        }
        __syncthreads();
        int co = t & 31, ph2 = t >> 5;
        #pragma unroll
        for (int r = 0; r < 8; ++r) {
            int pl = r * 8 + ph2;
            uint4 v = *(const uint4*)&ltile[pl * 132 + ((co * 4) ^ ((pl & 7) << 2))];
            *(uint4*)(ht + ((size_t)b * HW_ + px0 + pl) * C_ + co * 8) = v;
        }
    }
}

// ---------------------------------------------------------------------------
// K4: fused deformable layer -- r12-proven (round-3 loop + non-atomic
// per-row gn-stat partials when pstats != nullptr).
// ---------------------------------------------------------------------------
__global__ __launch_bounds__(1024, 4) void deform_fused_kernel(
    const short* __restrict__ ht,   const short* __restrict__ fdw,
    const short* __restrict__ ppk,  const float* __restrict__ pwb,
    const short* __restrict__ wp,   const float* __restrict__ bias,
    const float* __restrict__ resid, float* __restrict__ outf,
    short* __restrict__ outb,       float* __restrict__ pstats)
{
    int lb = ((blockIdx.x & 7) << 5) | (blockIdx.x >> 3);   // XCD swizzle
    int b = lb >> 6;
    int row = lb & 63;
    __shared__ int   i00[576], i01[576], i10[576], i11[576];
    __shared__ float c00[576], c01[576], c10[576], c11[576];
    __shared__ __align__(16) short sbuf[2][2][8192];  // 64KB
    __shared__ float stat_lds[16][8];
    float* off_lds = (float*)&sbuf[0][0][0];
    int t = threadIdx.x;
    int wv = t >> 6, lane = t & 63;
    int pq = lane >> 4, pr = lane & 15;
    int l31 = lane & 31, hi = lane >> 5;

    // ---- stage A: pw offsets via 16x16x32 MFMA (waves 0..7, full C) ----
    if (wv < 8) {
        int ot = wv & 1, ptw = wv >> 1;
        int px = ptw * 16 + pr;
        const short8* fdw8 = (const short8*)fdw;
        size_t fbase = ((size_t)(b * 64 + row)) * 32;
        const short8* ap = (const short8*)ppk;
        floatx4 pacc = (floatx4){0.f, 0.f, 0.f, 0.f};
        #pragma unroll
        for (int sl = 0; sl < 8; ++sl) {
            short8 af = ap[(sl * 2 + ot) * 64 + lane];
            short8 bf = fdw8[(fbase + sl * 4 + pq) * 64 + px];
            pacc = __builtin_amdgcn_mfma_f32_16x16x32_bf16(af, bf, pacc, 0, 0, 0);
        }
        #pragma unroll
        for (int r = 0; r < 4; ++r) {
            int o = ot * 16 + pq * 4 + r;
            if (o < NOFF_) off_lds[o * 64 + px] = pacc[r] + pwb[o];
        }
    }
    __syncthreads();

    // ---- stage B: bilinear coefficient tables ----
    if (t < 576) {
        int e = t;
        int k = e >> 6, p = e & 63;
        float offy = off_lds[(2 * k) * 64 + p];
        float offx = off_lds[(2 * k + 1) * 64 + p];
        float py = (float)row + (float)(k / 3 - 1) + offy;
        float px = (float)p   + (float)(k % 3 - 1) + offx;
        float y0f = floorf(py), x0f = floorf(px);
        float wy1 = py - y0f, wx1 = px - x0f;
        float wy0 = 1.f - wy1, wx0 = 1.f - wx1;
        float y1f = y0f + 1.f, x1f = x0f + 1.f;
        bool vy0 = (y0f >= 0.f) && (y0f <= 63.f);
        bool vy1 = (y1f >= 0.f) && (y1f <= 63.f);
        bool vx0 = (x0f >= 0.f) && (x0f <= 63.f);
        bool vx1 = (x1f >= 0.f) && (x1f <= 63.f);
        int iy0 = (int)fminf(fmaxf(y0f, 0.f), 63.f);
        int iy1 = (int)fminf(fmaxf(y1f, 0.f), 63.f);
        int ix0 = (int)fminf(fmaxf(x0f, 0.f), 63.f);
        int ix1 = (int)fminf(fmaxf(x1f, 0.f), 63.f);
        i00[e] = iy0 * 64 + ix0; i01[e] = iy0 * 64 + ix1;
        i10[e] = iy1 * 64 + ix0; i11[e] = iy1 * 64 + ix1;
        c00[e] = (vy0 && vx0) ? wy0 * wx0 : 0.f;
        c01[e] = (vy0 && vx1) ? wy0 * wx1 : 0.f;
        c10[e] = (vy1 && vx0) ? wy1 * wx0 : 0.f;
        c11[e] = (vy1 && vx1) ? wy1 * wx1 : 0.f;
    }
    __syncthreads();

    // ---- stage C: 9 taps, full C, double-buffered ----
    int c8a = t & 7;
    int pan = (t >> 3) & 1;
    int spx = t >> 4;                       // 0..63
    const short* hb0 = ht + ((size_t)b * HW_) * C_ + pan * 128 + c8a * 8;
    const short* hb1 = hb0 + 64;            // octet +8
    int slotA = (c8a ^ (spx & 15)) * 8;
    int slotB = ((c8a + 8) ^ (spx & 15)) * 8;
    int srow = spx * 128;

    short8 ra[4], rb[4];
    auto prefetch = [&](int g) {
        int e = g * 64 + spx;
        int a00 = i00[e], a01 = i01[e], a10 = i10[e], a11 = i11[e];
        ra[0] = *(const short8*)(hb0 + (size_t)a00 * C_);
        ra[1] = *(const short8*)(hb0 + (size_t)a01 * C_);
        ra[2] = *(const short8*)(hb0 + (size_t)a10 * C_);
        ra[3] = *(const short8*)(hb0 + (size_t)a11 * C_);
        rb[0] = *(const short8*)(hb1 + (size_t)a00 * C_);
        rb[1] = *(const short8*)(hb1 + (size_t)a01 * C_);
        rb[2] = *(const short8*)(hb1 + (size_t)a10 * C_);
        rb[3] = *(const short8*)(hb1 + (size_t)a11 * C_);
    };
    auto stage_write = [&](int g, int bi) {
        int e = g * 64 + spx;
        float w00 = c00[e], w01 = c01[e], w10 = c10[e], w11 = c11[e];
        uint4 va, vb;
        float f0, f1;
        #define BLEND(R, J) (w00 * bf2f(R[0][J]) + w01 * bf2f(R[1][J]) \
                           + w10 * bf2f(R[2][J]) + w11 * bf2f(R[3][J]))
        f0 = BLEND(ra, 0); f1 = BLEND(ra, 1); va.x = pkbf(f0, f1);
        f0 = BLEND(ra, 2); f1 = BLEND(ra, 3); va.y = pkbf(f0, f1);
        f0 = BLEND(ra, 4); f1 = BLEND(ra, 5); va.z = pkbf(f0, f1);
        f0 = BLEND(ra, 6); f1 = BLEND(ra, 7); va.w = pkbf(f0, f1);
        f0 = BLEND(rb, 0); f1 = BLEND(rb, 1); vb.x = pkbf(f0, f1);
        f0 = BLEND(rb, 2); f1 = BLEND(rb, 3); vb.y = pkbf(f0, f1);
        f0 = BLEND(rb, 4); f1 = BLEND(rb, 5); vb.z = pkbf(f0, f1);
        f0 = BLEND(rb, 6); f1 = BLEND(rb, 7); vb.w = pkbf(f0, f1);
        #undef BLEND
        short* sp = &sbuf[bi][pan][srow];
        *(uint4*)&sp[slotA] = va;
        *(uint4*)&sp[slotB] = vb;
    };

    int pairId = wv & 7;
    int half = wv >> 3;

    floatx16 acc[2];
    #pragma unroll
    for (int i = 0; i < 16; ++i) { acc[0][i] = 0.f; acc[1][i] = 0.f; }

    prefetch(0);
    stage_write(0, 0);
    prefetch(1);
    __syncthreads();

    const short8* wp8 = (const short8*)wp;
    int msk = l31 & 15;

    for (int g = 0; g < 9; ++g) {
        const short* sb = &sbuf[g & 1][half][0];
        #pragma unroll
        for (int q4 = 0; q4 < 2; ++q4) {
            short8 af[4];
            #pragma unroll
            for (int qq = 0; qq < 4; ++qq)
                af[qq] = wp8[(size_t)(((g * 16 + half * 8 + q4 * 4 + qq) * 8 + pairId) * 64 + lane)];
            #pragma unroll
            for (int qq = 0; qq < 4; ++qq) {
                int ksl = q4 * 4 + qq;                       // local slab 0..7
                int so = ((((ksl << 1) | hi) ^ msk) << 3);
                short8 b0 = *(const short8*)&sb[l31 * 128 + so];
                short8 b1 = *(const short8*)&sb[(32 + l31) * 128 + so];
                acc[0] = __builtin_amdgcn_mfma_f32_32x32x16_bf16(af[qq], b0, acc[0], 0, 0, 0);
                acc[1] = __builtin_amdgcn_mfma_f32_32x32x16_bf16(af[qq], b1, acc[1], 0, 0, 0);
            }
        }
        if (g + 1 < 9) {
            stage_write(g + 1, (g + 1) & 1);
            if (g + 2 < 9) prefetch(g + 2);
        }
        __syncthreads();
    }

    // ---- combine K-halves in LDS ----
    float* xch = (float*)&sbuf[0][0][0];
    int wreg = (pairId * 2 + half) * 1024;
    floatx16 aw = half ? acc[0] : acc[1];
    floatx4* xq = (floatx4*)xch;
    #pragma unroll
    for (int j = 0; j < 4; ++j) {
        floatx4 v = {aw[j * 4 + 0], aw[j * 4 + 1], aw[j * 4 + 2], aw[j * 4 + 3]};
        xq[(wreg >> 2) + j * 64 + lane] = v;
    }
    __syncthreads();
    int rreg = (pairId * 2 + (half ^ 1)) * 1024;
    floatx16 ac = half ? acc[1] : acc[0];
    #pragma unroll
    for (int j = 0; j < 4; ++j) {
        floatx4 v = xq[(rreg >> 2) + j * 64 + lane];
        ac[j * 4 + 0] += v.x; ac[j * 4 + 1] += v.y;
        ac[j * 4 + 2] += v.z; ac[j * 4 + 3] += v.w;
    }

    // ---- epilogue: store px-tile; optional gn-stat partials ----
    float sj[4] = {0.f, 0.f, 0.f, 0.f};
    float qj[4] = {0.f, 0.f, 0.f, 0.f};
    #pragma unroll
    for (int r = 0; r < 16; ++r) {
        int o = pairId * 32 + (r & 3) + 8 * (r >> 2) + 4 * hi;
        float v = ac[r] + bias[o];
        size_t ob = ((size_t)(b * C_ + o)) * HW_ + row * 64 + half * 32 + l31;
        if (outf) {
            if (resid) v += resid[ob];
            outf[ob] = v;
        } else {
            outb[ob] = f2bf(v);
            sj[r >> 2] += v;
            qj[r >> 2] += v * v;
        }
    }
    if (pstats) {
        #pragma unroll
        for (int off = 32; off > 0; off >>= 1) {
            #pragma unroll
            for (int j = 0; j < 4; ++j) {
                sj[j] += __shfl_down(sj[j], off, 64);
                qj[j] += __shfl_down(qj[j], off, 64);
            }
        }
        if (lane == 0) {
            #pragma unroll
            for (int j = 0; j < 4; ++j) {
                stat_lds[wv][j] = sj[j];
                stat_lds[wv][4 + j] = qj[j];
            }
        }
        __syncthreads();
        if (t < 32) {
            int pid = t >> 2, j = t & 3;
            float sT = stat_lds[pid][j] + stat_lds[pid + 8][j];
            float qT = stat_lds[pid][4 + j] + stat_lds[pid + 8][4 + j];
            float* pp = pstats + (((size_t)(b * 64 + row)) * 32 + pid * 4 + j) * 2;
            pp[0] = sT;
            pp[1] = qT;
        }
    }
}

// ---------------------------------------------------------------------------
extern "C" void kernel_launch(void* const* d_in, const int* in_sizes, int n_in,
                              void* d_out, int out_size, void* d_ws, size_t ws_size,
                              hipStream_t stream)
{
    const float* x     = (const float*)d_in[0];
    const float* gn1_g = (const float*)d_in[1];
    const float* gn1_b = (const float*)d_in[2];
    const float* dw1   = (const float*)d_in[3];
    const float* pw1   = (const float*)d_in[4];
    const float* pwb1  = (const float*)d_in[5];
    const float* w1    = (const float*)d_in[6];
    const float* b1    = (const float*)d_in[7];
    const float* gn2_g = (const float*)d_in[8];
    const float* gn2_b = (const float*)d_in[9];
    const float* dw2   = (const float*)d_in[10];
    const float* pw2   = (const float*)d_in[11];
    const float* pwb2  = (const float*)d_in[12];
    const float* w2    = (const float*)d_in[13];
    const float* b2    = (const float*)d_in[14];
    float* out = (float*)d_out;

    float* ws   = (float*)d_ws;
    short* y1b  = (short*)ws;                  // bf16 [B][C][HW]       (8 MB)
    short* hbt  = (short*)(ws + 4194304);      // bf16 [B][HW][C]       (8 MB)
    short* fdwt = (short*)(ws + 8388608);      // bf16 [B][64][32][64][8] (8 MB)
    short* wp1  = (short*)(ws + 10485760);     // 589,824 bf16
    short* wp2  = (short*)(ws + 10780672);     // 589,824 bf16
    short* ppk1 = (short*)(ws + 11075584);     // 8,192 bf16
    short* ppk2 = (short*)(ws + 11079680);     // 8,192 bf16
    float* pstats  = ws + 11083776;            // [B][64][32][2] = 16384 floats
    float* gstats1 = ws + 11100160;            // [2][128] = 256 floats

    // wpack + gn1 stats (one launch)
    wpack_gn1_kernel<<<4800, 256, 0, stream>>>(w1, w2, pw1, pw2,
                                               wp1, wp2, ppk1, ppk2,
                                               x, gstats1);

    // layer 1: gn1-apply fused into dw7t loads (fp32 x direct)
    dw7t_tr_f32_kernel<<<512, 256, 0, stream>>>(x, dw1, fdwt, hbt,
                                                gstats1, gn1_g, gn1_b);
    deform_fused_kernel<<<B_ * H_, 1024, 0, stream>>>(
        hbt, fdwt, ppk1, pwb1, wp1, b1, nullptr, nullptr, y1b, pstats);

    // layer 2 (+ residual x): gn2-apply fused into dw7t loads
    dw7t_tr_kernel<<<512, 256, 0, stream>>>(y1b, dw2, fdwt, hbt,
                                            pstats, gn2_g, gn2_b);
    deform_fused_kernel<<<B_ * H_, 1024, 0, stream>>>(
        hbt, fdwt, ppk2, pwb2, wp2, b2, x, out, nullptr, nullptr);
}

// Round 14
// 236.000 us; speedup vs baseline: 1.0259x; 1.0259x over previous
//
#include <hip/hip_runtime.h>

#define B_    4
#define C_    256
#define H_    64
#define W_    64
#define HW_   4096
#define NG_   32
#define CPG_  8
#define KK_   9
#define NOFF_ 18

typedef __attribute__((ext_vector_type(8))) short short8;
typedef __attribute__((ext_vector_type(4))) short short4v;
typedef __attribute__((ext_vector_type(4))) float floatx4;
typedef __attribute__((ext_vector_type(16))) float floatx16;

static __device__ __forceinline__ short f2bf(float f) {
    union { float f; unsigned u; } v; v.f = f;
    unsigned r = v.u + 0x7fff + ((v.u >> 16) & 1);   // RNE
    return (short)(r >> 16);
}
static __device__ __forceinline__ float bf2f(short s) {
    union { unsigned u; float f; } v;
    v.u = ((unsigned)(unsigned short)s) << 16;
    return v.f;
}
// packed f32x2 -> bf16x2 (RNE), single VALU op
static __device__ __forceinline__ unsigned pkbf(float lo, float hi) {
    unsigned r;
    asm("v_cvt_pk_bf16_f32 %0, %1, %2" : "=v"(r) : "v"(lo), "v"(hi));
    return r;
}

// ---------------------------------------------------------------------------
// K1: GroupNorm (32 groups) + ReLU -> bf16 [C][HW]. fp32-input, LDS-cached:
// the (b,group) slab (128 KB) stays in LDS so the normalize pass does not
// re-read global. (r11/r12-proven)
// ---------------------------------------------------------------------------
__global__ __launch_bounds__(1024) void gn_relu_f32_kernel(
    const float* __restrict__ in, const float* __restrict__ gamma,
    const float* __restrict__ beta, short* __restrict__ outb)
{
    __shared__ float cache[32768];         // 128 KB
    __shared__ float red[32];
    __shared__ float sh_rs, sh_m;
    int b = blockIdx.x >> 5;
    int g = blockIdx.x & 31;
    const int N = CPG_ * HW_;              // 32768
    size_t base = ((size_t)(b * C_ + g * CPG_)) * HW_;
    const float4* in4 = (const float4*)(in + base);
    int t = threadIdx.x;

    float s = 0.f, ss = 0.f;
    for (int i = t; i < N / 4; i += 1024) {
        float4 v = in4[i];
        *(float4*)&cache[i * 4] = v;
        s  += v.x + v.y + v.z + v.w;
        ss += v.x * v.x + v.y * v.y + v.z * v.z + v.w * v.w;
    }
    #pragma unroll
    for (int off = 32; off > 0; off >>= 1) {
        s  += __shfl_down(s, off, 64);
        ss += __shfl_down(ss, off, 64);
    }
    int wid = t >> 6;
    if ((t & 63) == 0) { red[wid] = s; red[16 + wid] = ss; }
    __syncthreads();
    if (t == 0) {
        float S = 0.f, SS = 0.f;
        #pragma unroll
        for (int i = 0; i < 16; ++i) { S += red[i]; SS += red[16 + i]; }
        float m = S / (float)N;
        float var = SS / (float)N - m * m;
        sh_rs = rsqrtf(var + 1e-5f);
        sh_m = m;
    }
    __syncthreads();
    float rs = sh_rs, m = sh_m;
    short4v* out4 = (short4v*)(outb + base);
    for (int i = t; i < N / 4; i += 1024) {
        int ch = g * CPG_ + (i >> 10);
        float ga = gamma[ch] * rs;
        float be = beta[ch] - m * ga;
        float4 v = *(const float4*)&cache[i * 4];
        short4v o;
        o.x = f2bf(fmaxf(fmaf(v.x, ga, be), 0.f));
        o.y = f2bf(fmaxf(fmaf(v.y, ga, be), 0.f));
        o.z = f2bf(fmaxf(fmaf(v.z, ga, be), 0.f));
        o.w = f2bf(fmaxf(fmaf(v.w, ga, be), 0.f));
        out4[i] = o;
    }
}

// ---------------------------------------------------------------------------
// K2: fused {depthwise 7x7 -> fdwt octet-major} AND {transpose -> ht
// [B][HW][C]}. Blocks 0..255: dw7t. Blocks 256..511: trA (XCD-swizzled).
// When pstats != nullptr (layer 2), fused GroupNorm-apply on the input:
// each block reduces deform-1's per-row group partials and applies
// relu(ga*v+be) on load. (r12-proven)
// ---------------------------------------------------------------------------
__global__ __launch_bounds__(256) void dw7t_tr_kernel(
    const short* __restrict__ in,   // layer1: hbf; layer2: y1b  [B][C][HW]
    const float* __restrict__ dwk,  // [C][49]
    short* __restrict__ fdwt,       // [B][64][32][64][8]
    short* __restrict__ ht,         // [B][HW][C]
    const float* __restrict__ pstats,  // [B][64][32][2] or nullptr
    const float* __restrict__ gamma, const float* __restrict__ beta)
{
    __shared__ __align__(16) char smem[78144];
    const float Ninv = 1.f / (float)(CPG_ * HW_);
    int t = threadIdx.x;
    int blk = blockIdx.x;
    if (blk < 256) {
        short (*tile)[38][72] = (short(*)[38][72])smem;          // 43776 B
        float (*wk8)[49]      = (float(*)[49])(smem + 43776);    // 1568 B
        short (*outs)[2048]   = (short(*)[2048])(smem + 45344);  // 32768 B
        float* gsh            = (float*)(smem + 78112);          // 2 floats
        int b = blk >> 6, o8 = (blk >> 1) & 31, rh = blk & 1;
        int c0 = o8 * 8;
        // ---- group stats for this block's single group (o8) ----
        if (pstats && t < 64) {
            const float* pp = pstats + (((size_t)(b * 64 + t)) * 32 + o8) * 2;
            float s = pp[0], q = pp[1];
            #pragma unroll
            for (int off = 32; off > 0; off >>= 1) {
                s += __shfl_down(s, off, 64);
                q += __shfl_down(q, off, 64);
            }
            if (t == 0) {
                float m = s * Ninv;
                float var = q * Ninv - m * m;
                gsh[0] = m;
                gsh[1] = rsqrtf(var + 1e-5f);
            }
        }
        unsigned* tz = (unsigned*)smem;
        for (int i = t; i < 10944; i += 256) tz[i] = 0u;         // zero tile
        for (int i = t; i < 392; i += 256)
            wk8[i / 49][i % 49] = dwk[(c0 + i / 49) * 49 + (i % 49)];
        __syncthreads();
        float m_g = 0.f, rs_g = 0.f;
        if (pstats) { m_g = gsh[0]; rs_g = gsh[1]; }
        // load 8 planes, rows rh*32-3 .. rh*32+34 (halo), cols at +4 pad
        for (int ch = 0; ch < 8; ++ch) {
            const short* src = in + ((size_t)(b * C_ + c0 + ch)) * HW_;
            float ga = 0.f, be = 0.f;
            if (pstats) {
                ga = gamma[c0 + ch] * rs_g;
                be = beta[c0 + ch] - m_g * ga;
            }
            for (int i = t; i < 608; i += 256) {
                int rr = i >> 4, xq = i & 15;
                int ry = rh * 32 + rr - 3;
                if (ry >= 0 && ry < 64) {
                    short4v v = *(const short4v*)(src + ry * 64 + xq * 4);
                    if (pstats) {
                        v.x = f2bf(fmaxf(fmaf(bf2f(v.x), ga, be), 0.f));
                        v.y = f2bf(fmaxf(fmaf(bf2f(v.y), ga, be), 0.f));
                        v.z = f2bf(fmaxf(fmaf(bf2f(v.z), ga, be), 0.f));
                        v.w = f2bf(fmaxf(fmaf(bf2f(v.w), ga, be), 0.f));
                    }
                    *(short4v*)&tile[ch][rr][4 + xq * 4] = v;
                }
            }
        }
        __syncthreads();
        // compute: 4096 quads (ch,y,x0)
        for (int it = 0; it < 16; ++it) {
            int q = it * 256 + t;
            int ch = q >> 9, y = (q >> 4) & 31, x0 = (q & 15) << 2;
            float a0 = 0.f, a1 = 0.f, a2 = 0.f, a3 = 0.f;
            const float* wr0 = wk8[ch];
            #pragma unroll
            for (int dy = 0; dy < 7; ++dy) {
                const short* trw = &tile[ch][y + dy][x0];
                short4v s0 = *(const short4v*)trw;
                short4v s1 = *(const short4v*)(trw + 4);
                short4v s2 = *(const short4v*)(trw + 8);
                float r[12] = {bf2f(s0.x), bf2f(s0.y), bf2f(s0.z), bf2f(s0.w),
                               bf2f(s1.x), bf2f(s1.y), bf2f(s1.z), bf2f(s1.w),
                               bf2f(s2.x), bf2f(s2.y), bf2f(s2.z), bf2f(s2.w)};
                const float* wr = wr0 + dy * 7;
                #pragma unroll
                for (int dx = 0; dx < 7; ++dx) {
                    float wv = wr[dx];
                    a0 = fmaf(r[dx + 1], wv, a0);
                    a1 = fmaf(r[dx + 2], wv, a1);
                    a2 = fmaf(r[dx + 3], wv, a2);
                    a3 = fmaf(r[dx + 4], wv, a3);
                }
            }
            short4v o;
            o.x = f2bf(a0); o.y = f2bf(a1); o.z = f2bf(a2); o.w = f2bf(a3);
            *(short4v*)&outs[ch][y * 64 + x0] = o;
        }
        __syncthreads();
        // octet-major coalesced write: 2048 px-chunks of 16B
        for (int it = 0; it < 8; ++it) {
            int p = it * 256 + t;
            short8 v;
            #pragma unroll
            for (int ch = 0; ch < 8; ++ch) v[ch] = outs[ch][p];
            *(short8*)(fdwt + (((size_t)(b * 64 + rh * 32 + (p >> 6)) * 32 + o8) * 64
                               + (p & 63)) * 8) = v;
        }
    } else {
        unsigned* ltile = (unsigned*)smem;     // 64*132 words = 33792 B
        float* gmrs = (float*)(smem + 65536);  // 64 floats (m | rs)
        int q0 = blk - 256;
        int q = ((q0 & 7) << 5) | (q0 >> 3);   // XCD swizzle (matches deform)
        int b = q >> 6;
        int px0 = (q & 63) * 64;
        const short* sb = in + (size_t)b * C_ * HW_;
        // ---- per-group stats for all 32 groups (8 threads per group) ----
        if (pstats) {
            int gq = t >> 3, rq = t & 7;
            float s = 0.f, qs = 0.f;
            for (int rr = rq; rr < 64; rr += 8) {
                const float* pp = pstats + (((size_t)(b * 64 + rr)) * 32 + gq) * 2;
                s += pp[0]; qs += pp[1];
            }
            s  += __shfl_down(s, 4, 64);  qs += __shfl_down(qs, 4, 64);
            s  += __shfl_down(s, 2, 64);  qs += __shfl_down(qs, 2, 64);
            s  += __shfl_down(s, 1, 64);  qs += __shfl_down(qs, 1, 64);
            if (rq == 0) {
                float m = s * Ninv;
                float var = qs * Ninv - m * m;
                gmrs[gq] = m;
                gmrs[32 + gq] = rsqrtf(var + 1e-5f);
            }
        }
        __syncthreads();
        int pq4 = t & 15, cphi = t >> 4;
        #pragma unroll
        for (int i = 0; i < 8; ++i) {
            int cp = i * 16 + cphi;            // channel pair 0..127
            const short* r0 = sb + (size_t)(2 * cp) * HW_ + px0 + pq4 * 4;
            short4v lo = *(const short4v*)r0;
            short4v hi = *(const short4v*)(r0 + HW_);
            float ga0 = 0.f, be0 = 0.f, ga1 = 0.f, be1 = 0.f;
            if (pstats) {
                int g0 = cp >> 2;
                float mm = gmrs[g0], rr2 = gmrs[32 + g0];
                ga0 = gamma[2 * cp] * rr2;     be0 = beta[2 * cp] - mm * ga0;
                ga1 = gamma[2 * cp + 1] * rr2; be1 = beta[2 * cp + 1] - mm * ga1;
            }
            #pragma unroll
            for (int j = 0; j < 4; ++j) {
                int pl = pq4 * 4 + j;
                unsigned wrd;
                if (pstats) {
                    float v0 = fmaxf(fmaf(bf2f(lo[j]), ga0, be0), 0.f);
                    float v1 = fmaxf(fmaf(bf2f(hi[j]), ga1, be1), 0.f);
                    wrd = pkbf(v0, v1);
                } else {
                    wrd = (unsigned)(unsigned short)lo[j]
                        | ((unsigned)(unsigned short)hi[j] << 16);
                }
                ltile[pl * 132 + (cp ^ ((pl & 7) << 2))] = wrd;
            }
        }
        __syncthreads();
        int co = t & 31, ph2 = t >> 5;
        #pragma unroll
        for (int r = 0; r < 8; ++r) {
            int pl = r * 8 + ph2;
            uint4 v = *(const uint4*)&ltile[pl * 132 + ((co * 4) ^ ((pl & 7) << 2))];
            *(uint4*)(ht + ((size_t)b * HW_ + px0 + pl) * C_ + co * 8) = v;
        }
    }
}

// ---------------------------------------------------------------------------
// K3: pack weights. Coalesced fp32 reads, scattered 2B writes.
// ---------------------------------------------------------------------------
__global__ __launch_bounds__(256) void wpack_all_kernel(
    const float* __restrict__ w1, const float* __restrict__ w2,
    const float* __restrict__ pw1, const float* __restrict__ pw2,
    short* __restrict__ wp1, short* __restrict__ wp2,
    short* __restrict__ ppk1, short* __restrict__ ppk2)
{
    int blk = blockIdx.x;
    if (blk < 4608) {
        const float* w = (blk < 2304) ? w1 : w2;
        short* wp = (blk < 2304) ? wp1 : wp2;
        int src = (blk % 2304) * 256 + threadIdx.x;  // 0..589823, coalesced
        float v = w[src];
        int o = src / (C_ * KK_);                    // src = (o*C + c)*9 + g
        int r = src - o * (C_ * KK_);
        int c = r / KK_;
        int g = r - c * KK_;
        int ot   = o >> 5;
        int lane = (o & 31) | (((c >> 3) & 1) << 5);
        int j    = c & 7;
        int slab = g * 16 + (c >> 4);
        wp[(slab << 12) | (ot << 9) | (lane << 3) | j] = f2bf(v);
    } else {
        int q = blk - 4608;                          // 0..63
        const float* pw = (q < 32) ? pw1 : pw2;
        short* ppk = (q < 32) ? ppk1 : ppk2;
        int idx = (q & 31) * 256 + threadIdx.x;      // 0..8191
        int j = idx & 7, lane = (idx >> 3) & 63;
        int ot = (idx >> 9) & 1, sl = idx >> 10;     // 0..7
        int o = ot * 16 + (lane & 15);
        int k = sl * 32 + (lane >> 4) * 8 + j;
        ppk[idx] = (o < NOFF_) ? f2bf(pw[o * C_ + k]) : (short)0;
    }
}

// ---------------------------------------------------------------------------
// K4: fused deformable layer -- round-3 structure (proven floor). When
// pstats != nullptr (layer 1), the epilogue also writes this block's
// per-(b,row) group partial sums NON-atomically (one 64B store/block).
// ---------------------------------------------------------------------------
__global__ __launch_bounds__(1024, 4) void deform_fused_kernel(
    const short* __restrict__ ht,   const short* __restrict__ fdw,
    const short* __restrict__ ppk,  const float* __restrict__ pwb,
    const short* __restrict__ wp,   const float* __restrict__ bias,
    const float* __restrict__ resid, float* __restrict__ outf,
    short* __restrict__ outb,       float* __restrict__ pstats)
{
    int lb = ((blockIdx.x & 7) << 5) | (blockIdx.x >> 3);   // XCD swizzle
    int b = lb >> 6;
    int row = lb & 63;
    __shared__ int   i00[576], i01[576], i10[576], i11[576];
    __shared__ float c00[576], c01[576], c10[576], c11[576];
    __shared__ __align__(16) short sbuf[2][2][8192];  // [buf][panel][64px*128ch] = 64KB
    __shared__ float stat_lds[16][8];
    float* off_lds = (float*)&sbuf[0][0][0];          // 18*64 floats, dead before staging
    int t = threadIdx.x;
    int wv = t >> 6, lane = t & 63;
    int pq = lane >> 4, pr = lane & 15;
    int l31 = lane & 31, hi = lane >> 5;

    // ---- stage A: pw offsets via 16x16x32 MFMA (waves 0..7, full C) ----
    if (wv < 8) {
        int ot = wv & 1, ptw = wv >> 1;
        int px = ptw * 16 + pr;
        const short8* fdw8 = (const short8*)fdw;
        size_t fbase = ((size_t)(b * 64 + row)) * 32;
        const short8* ap = (const short8*)ppk;
        floatx4 pacc = (floatx4){0.f, 0.f, 0.f, 0.f};
        #pragma unroll
        for (int sl = 0; sl < 8; ++sl) {
            short8 af = ap[(sl * 2 + ot) * 64 + lane];
            short8 bf = fdw8[(fbase + sl * 4 + pq) * 64 + px];
            pacc = __builtin_amdgcn_mfma_f32_16x16x32_bf16(af, bf, pacc, 0, 0, 0);
        }
        #pragma unroll
        for (int r = 0; r < 4; ++r) {
            int o = ot * 16 + pq * 4 + r;
            if (o < NOFF_) off_lds[o * 64 + px] = pacc[r] + pwb[o];
        }
    }
    __syncthreads();

    // ---- stage B: bilinear coefficient tables ----
    if (t < 576) {
        int e = t;
        int k = e >> 6, p = e & 63;
        float offy = off_lds[(2 * k) * 64 + p];
        float offx = off_lds[(2 * k + 1) * 64 + p];
        float py = (float)row + (float)(k / 3 - 1) + offy;
        float px = (float)p   + (float)(k % 3 - 1) + offx;
        float y0f = floorf(py), x0f = floorf(px);
        float wy1 = py - y0f, wx1 = px - x0f;
        float wy0 = 1.f - wy1, wx0 = 1.f - wx1;
        float y1f = y0f + 1.f, x1f = x0f + 1.f;
        bool vy0 = (y0f >= 0.f) && (y0f <= 63.f);
        bool vy1 = (y1f >= 0.f) && (y1f <= 63.f);
        bool vx0 = (x0f >= 0.f) && (x0f <= 63.f);
        bool vx1 = (x1f >= 0.f) && (x1f <= 63.f);
        int iy0 = (int)fminf(fmaxf(y0f, 0.f), 63.f);
        int iy1 = (int)fminf(fmaxf(y1f, 0.f), 63.f);
        int ix0 = (int)fminf(fmaxf(x0f, 0.f), 63.f);
        int ix1 = (int)fminf(fmaxf(x1f, 0.f), 63.f);
        i00[e] = iy0 * 64 + ix0; i01[e] = iy0 * 64 + ix1;
        i10[e] = iy1 * 64 + ix0; i11[e] = iy1 * 64 + ix1;
        c00[e] = (vy0 && vx0) ? wy0 * wx0 : 0.f;
        c01[e] = (vy0 && vx1) ? wy0 * wx1 : 0.f;
        c10[e] = (vy1 && vx0) ? wy1 * wx0 : 0.f;
        c11[e] = (vy1 && vx1) ? wy1 * wx1 : 0.f;
    }
    __syncthreads();

    // ---- stage C: 9 taps, full C, double-buffered (round-3 proven) ----
    int c8a = t & 7;
    int pan = (t >> 3) & 1;
    int spx = t >> 4;                       // 0..63
    const short* hb0 = ht + ((size_t)b * HW_) * C_ + pan * 128 + c8a * 8;
    const short* hb1 = hb0 + 64;            // octet +8
    int slotA = (c8a ^ (spx & 15)) * 8;
    int slotB = ((c8a + 8) ^ (spx & 15)) * 8;
    int srow = spx * 128;

    short8 ra[4], rb[4];
    auto prefetch = [&](int g) {
        int e = g * 64 + spx;
        int a00 = i00[e], a01 = i01[e], a10 = i10[e], a11 = i11[e];
        ra[0] = *(const short8*)(hb0 + (size_t)a00 * C_);
        ra[1] = *(const short8*)(hb0 + (size_t)a01 * C_);
        ra[2] = *(const short8*)(hb0 + (size_t)a10 * C_);
        ra[3] = *(const short8*)(hb0 + (size_t)a11 * C_);
        rb[0] = *(const short8*)(hb1 + (size_t)a00 * C_);
        rb[1] = *(const short8*)(hb1 + (size_t)a01 * C_);
        rb[2] = *(const short8*)(hb1 + (size_t)a10 * C_);
        rb[3] = *(const short8*)(hb1 + (size_t)a11 * C_);
    };
    auto stage_write = [&](int g, int bi) {
        int e = g * 64 + spx;
        float w00 = c00[e], w01 = c01[e], w10 = c10[e], w11 = c11[e];
        uint4 va, vb;
        float f0, f1;
        #define BLEND(R, J) (w00 * bf2f(R[0][J]) + w01 * bf2f(R[1][J]) \
                           + w10 * bf2f(R[2][J]) + w11 * bf2f(R[3][J]))
        f0 = BLEND(ra, 0); f1 = BLEND(ra, 1); va.x = pkbf(f0, f1);
        f0 = BLEND(ra, 2); f1 = BLEND(ra, 3); va.y = pkbf(f0, f1);
        f0 = BLEND(ra, 4); f1 = BLEND(ra, 5); va.z = pkbf(f0, f1);
        f0 = BLEND(ra, 6); f1 = BLEND(ra, 7); va.w = pkbf(f0, f1);
        f0 = BLEND(rb, 0); f1 = BLEND(rb, 1); vb.x = pkbf(f0, f1);
        f0 = BLEND(rb, 2); f1 = BLEND(rb, 3); vb.y = pkbf(f0, f1);
        f0 = BLEND(rb, 4); f1 = BLEND(rb, 5); vb.z = pkbf(f0, f1);
        f0 = BLEND(rb, 6); f1 = BLEND(rb, 7); vb.w = pkbf(f0, f1);
        #undef BLEND
        short* sp = &sbuf[bi][pan][srow];
        *(uint4*)&sp[slotA] = va;
        *(uint4*)&sp[slotB] = vb;
    };

    // wave role: pairId = o-tile (32 rows), half = K-half (128 channels)
    int pairId = wv & 7;
    int half = wv >> 3;

    floatx16 acc[2];
    #pragma unroll
    for (int i = 0; i < 16; ++i) { acc[0][i] = 0.f; acc[1][i] = 0.f; }

    prefetch(0);
    stage_write(0, 0);
    prefetch(1);
    __syncthreads();

    const short8* wp8 = (const short8*)wp;
    int msk = l31 & 15;

    for (int g = 0; g < 9; ++g) {
        const short* sb = &sbuf[g & 1][half][0];
        #pragma unroll
        for (int q4 = 0; q4 < 2; ++q4) {
            short8 af[4];
            #pragma unroll
            for (int qq = 0; qq < 4; ++qq)
                af[qq] = wp8[(size_t)(((g * 16 + half * 8 + q4 * 4 + qq) * 8 + pairId) * 64 + lane)];
            #pragma unroll
            for (int qq = 0; qq < 4; ++qq) {
                int ksl = q4 * 4 + qq;                       // local slab 0..7
                int so = ((((ksl << 1) | hi) ^ msk) << 3);
                short8 b0 = *(const short8*)&sb[l31 * 128 + so];
                short8 b1 = *(const short8*)&sb[(32 + l31) * 128 + so];
                acc[0] = __builtin_amdgcn_mfma_f32_32x32x16_bf16(af[qq], b0, acc[0], 0, 0, 0);
                acc[1] = __builtin_amdgcn_mfma_f32_32x32x16_bf16(af[qq], b1, acc[1], 0, 0, 0);
            }
        }
        if (g + 1 < 9) {
            stage_write(g + 1, (g + 1) & 1);
            if (g + 2 < 9) prefetch(g + 2);
        }
        __syncthreads();
    }

    // ---- combine K-halves in LDS (lane-major planes, conflict-free) ----
    float* xch = (float*)&sbuf[0][0][0];     // 16 regions x 4KB = 64KB
    int wreg = (pairId * 2 + half) * 1024;   // floats
    floatx16 aw = half ? acc[0] : acc[1];
    floatx4* xq = (floatx4*)xch;
    #pragma unroll
    for (int j = 0; j < 4; ++j) {
        floatx4 v = {aw[j * 4 + 0], aw[j * 4 + 1], aw[j * 4 + 2], aw[j * 4 + 3]};
        xq[(wreg >> 2) + j * 64 + lane] = v;
    }
    __syncthreads();
    int rreg = (pairId * 2 + (half ^ 1)) * 1024;
    floatx16 ac = half ? acc[1] : acc[0];
    #pragma unroll
    for (int j = 0; j < 4; ++j) {
        floatx4 v = xq[(rreg >> 2) + j * 64 + lane];
        ac[j * 4 + 0] += v.x; ac[j * 4 + 1] += v.y;
        ac[j * 4 + 2] += v.z; ac[j * 4 + 3] += v.w;
    }

    // ---- epilogue: store px-tile; optional gn-stats partials (group =
    // pairId*4 + (r>>2), compile-time under the unroll).
    float sj[4] = {0.f, 0.f, 0.f, 0.f};
    float qj[4] = {0.f, 0.f, 0.f, 0.f};
    #pragma unroll
    for (int r = 0; r < 16; ++r) {
        int o = pairId * 32 + (r & 3) + 8 * (r >> 2) + 4 * hi;
        float v = ac[r] + bias[o];
        size_t ob = ((size_t)(b * C_ + o)) * HW_ + row * 64 + half * 32 + l31;
        if (outf) {
            if (resid) v += resid[ob];
            outf[ob] = v;
        } else {
            outb[ob] = f2bf(v);
            sj[r >> 2] += v;
            qj[r >> 2] += v * v;
        }
    }
    if (pstats) {
        #pragma unroll
        for (int off = 32; off > 0; off >>= 1) {
            #pragma unroll
            for (int j = 0; j < 4; ++j) {
                sj[j] += __shfl_down(sj[j], off, 64);
                qj[j] += __shfl_down(qj[j], off, 64);
            }
        }
        if (lane == 0) {
            #pragma unroll
            for (int j = 0; j < 4; ++j) {
                stat_lds[wv][j] = sj[j];
                stat_lds[wv][4 + j] = qj[j];
            }
        }
        __syncthreads();
        if (t < 32) {
            int pid = t >> 2, j = t & 3;
            float sT = stat_lds[pid][j] + stat_lds[pid + 8][j];
            float qT = stat_lds[pid][4 + j] + stat_lds[pid + 8][4 + j];
            float* pp = pstats + (((size_t)(b * 64 + row)) * 32 + pid * 4 + j) * 2;
            pp[0] = sT;
            pp[1] = qT;
        }
    }
}

// ---------------------------------------------------------------------------
extern "C" void kernel_launch(void* const* d_in, const int* in_sizes, int n_in,
                              void* d_out, int out_size, void* d_ws, size_t ws_size,
                              hipStream_t stream)
{
    const float* x     = (const float*)d_in[0];
    const float* gn1_g = (const float*)d_in[1];
    const float* gn1_b = (const float*)d_in[2];
    const float* dw1   = (const float*)d_in[3];
    const float* pw1   = (const float*)d_in[4];
    const float* pwb1  = (const float*)d_in[5];
    const float* w1    = (const float*)d_in[6];
    const float* b1    = (const float*)d_in[7];
    const float* gn2_g = (const float*)d_in[8];
    const float* gn2_b = (const float*)d_in[9];
    const float* dw2   = (const float*)d_in[10];
    const float* pw2   = (const float*)d_in[11];
    const float* pwb2  = (const float*)d_in[12];
    const float* w2    = (const float*)d_in[13];
    const float* b2    = (const float*)d_in[14];
    float* out = (float*)d_out;

    float* ws   = (float*)d_ws;
    short* y1b  = (short*)ws;                  // bf16 [B][C][HW]       (8 MB)
    short* hbf  = (short*)(ws + 2097152);      // bf16 [B][C][HW]       (8 MB)
    short* hbt  = (short*)(ws + 4194304);      // bf16 [B][HW][C]       (8 MB)
    short* fdwt = (short*)(ws + 8388608);      // bf16 [B][64][32][64][8] (8 MB)
    short* wp1  = (short*)(ws + 10485760);     // 589,824 bf16
    short* wp2  = (short*)(ws + 10780672);     // 589,824 bf16
    short* ppk1 = (short*)(ws + 11075584);     // 8,192 bf16
    short* ppk2 = (short*)(ws + 11079680);     // 8,192 bf16
    float* pstats = ws + 11083776;             // [B][64][32][2] = 16384 floats

    wpack_all_kernel<<<4672, 256, 0, stream>>>(w1, w2, pw1, pw2,
                                               wp1, wp2, ppk1, ppk2);

    // layer 1 (deform-1 epilogue writes per-row gn2 stat partials)
    gn_relu_f32_kernel<<<B_ * NG_, 1024, 0, stream>>>(x, gn1_g, gn1_b, hbf);
    dw7t_tr_kernel<<<512, 256, 0, stream>>>(hbf, dw1, fdwt, hbt,
                                            nullptr, nullptr, nullptr);
    deform_fused_kernel<<<B_ * H_, 1024, 0, stream>>>(
        hbt, fdwt, ppk1, pwb1, wp1, b1, nullptr, nullptr, y1b, pstats);

    // layer 2 (+ residual x): gn2 apply is fused into dw7t_tr's loads
    dw7t_tr_kernel<<<512, 256, 0, stream>>>(y1b, dw2, fdwt, hbt,
                                            pstats, gn2_g, gn2_b);
    deform_fused_kernel<<<B_ * H_, 1024, 0, stream>>>(
        hbt, fdwt, ppk2, pwb2, wp2, b2, x, out, nullptr, nullptr);
}